// Round 1
// baseline (229.197 us; speedup 1.0000x reference)
//
#include <hip/hip_runtime.h>

#define D_MODEL 1024
#define HEADS   16
#define DK      64
#define BATCH   2
#define TSEQ    2048
#define NTOK    (BATCH * TSEQ)   // 4096

typedef __attribute__((ext_vector_type(8))) short bf16x8;
typedef __attribute__((ext_vector_type(4))) short s16x4;
typedef __attribute__((ext_vector_type(4))) float f32x4;
typedef __attribute__((ext_vector_type(2))) unsigned u32x2;
typedef __attribute__((ext_vector_type(4))) unsigned u32x4;

__device__ __forceinline__ short f2bf(float f) {
    union { float f; unsigned u; } a;
    a.f = f;
    unsigned r = a.u + 0x7FFFu + ((a.u >> 16) & 1u);
    return (short)(r >> 16);
}
// pack two non-negative floats to bf16x2 (round-to-nearest, ties away)
__device__ __forceinline__ unsigned pk_bf16_rn(float a, float b) {
    union { float f; unsigned u; } x, y;
    x.f = a; y.f = b;
    return __builtin_amdgcn_perm(y.u + 0x8000u, x.u + 0x8000u, 0x07060302u);
}

// async global->LDS, 16B per lane. LDS dest = wave-uniform base + lane*16.
__device__ __forceinline__ void gl_lds16(const void* g, void* l) {
    __builtin_amdgcn_global_load_lds(
        (const __attribute__((address_space(1))) unsigned int*)(unsigned long long)g,
        (__attribute__((address_space(3))) unsigned int*)(unsigned int)(unsigned long long)l,
        16, 0, 0);
}

// after pl_swap(a=R[b], b=R[b+1]) (b in {0,2}):
//   a = fragment word for source-parity p=0, b = word for p=1
// i.e. lane group g receives R[b + (g>>1)] taken from lane group 2*(g&1)+p.
// (permlane32_swap: vdst lanes 32-63 <-> src lanes 0-31;
//  permlane16_swap: vdst rows 1,3   <-> src rows 0,2)
__device__ __forceinline__ void pl_swap(unsigned& a, unsigned& b) {
    u32x2 r32 = __builtin_amdgcn_permlane32_swap(a, b, false, false);
    u32x2 r16 = __builtin_amdgcn_permlane16_swap(r32[0], r32[1], false, false);
    a = r16[0]; b = r16[1];
}

// ------------------------------------------------- fused prep: transposes + cvt
__global__ __launch_bounds__(256) void prep_kernel(
    const float* __restrict__ x, const float* __restrict__ Wqkv,
    const float* __restrict__ Wout,
    short* __restrict__ xb, short* __restrict__ wqkvt, short* __restrict__ woutt)
{
    int bx = blockIdx.x;
    if (bx < 4096) {
        __shared__ float tile[32][33];
        const float* in; short* out; int N, n0, k0;
        if (bx < 3072) { in = Wqkv; out = wqkvt; N = 3072; n0 = (bx % 96) * 32; k0 = (bx / 96) * 32; }
        else { int t2 = bx - 3072; in = Wout; out = woutt; N = 1024; n0 = (t2 & 31) * 32; k0 = (t2 >> 5) * 32; }
        int tx = threadIdx.x & 31, ty = threadIdx.x >> 5;
        #pragma unroll
        for (int i = 0; i < 32; i += 8)
            tile[ty + i][tx] = in[(long)(k0 + ty + i) * N + n0 + tx];
        __syncthreads();
        #pragma unroll
        for (int i = 0; i < 32; i += 8)
            out[(long)(n0 + ty + i) * 1024 + k0 + tx] = f2bf(tile[tx][ty + i]);
    } else {
        long i = ((long)(bx - 4096) * 256 + threadIdx.x) * 4;
        float4 v = *(const float4*)&x[i];
        s16x4 o;
        o[0] = f2bf(v.x); o[1] = f2bf(v.y); o[2] = f2bf(v.z); o[3] = f2bf(v.w);
        *(s16x4*)&xb[i] = o;
    }
}

// ---------------------------------------------------------------- bf16 MFMA GEMM
// Fragment-major LDS: tile stored as 16 blocks of 1KiB, block n = wm*8+i*2+c.
// Each lane's global_load_lds SOURCE is the exact 16B it later consumes as its
// MFMA fragment chunk -> staging writes linear AND fragment reads are contiguous
// 1KiB per wave instruction: zero bank conflicts, no swizzle math.
// MODE 0: QKV epilogue -> q (pre-scaled by log2e/8), k, vt[(b*16+h)*64+d][2048]
// MODE 1: out-proj     -> fp32 out[tok][1024]
template<int MODE>
__global__ __launch_bounds__(256) void gemm_bf16_kernel(
    const short* __restrict__ A, const short* __restrict__ Bt,
    const float* __restrict__ bias,
    short* __restrict__ qo, short* __restrict__ ko, short* __restrict__ vt,
    float* __restrict__ fout)
{
    const int K = 1024;
    __shared__ short As[16 * 512];   // [block n = wm*8+i*2+c][lane*8 shorts]
    __shared__ short Bs[16 * 512];

    int tid  = threadIdx.x;
    int wid  = tid >> 6, lane = tid & 63;
    int wm   = wid >> 1, wn   = wid & 1;
    int g    = lane >> 4, l15 = lane & 15;
    long m0  = (long)blockIdx.x * 128;
    long n0  = (long)blockIdx.y * 128;

    f32x4 acc[4][4];
    #pragma unroll
    for (int i = 0; i < 4; i++)
        #pragma unroll
        for (int j = 0; j < 4; j++)
            acc[i][j] = (f32x4){0.f, 0.f, 0.f, 0.f};

    // wave wid stages fragment blocks n = wid*4 + s (s=0..3) of both tiles.
    // block n <-> (wm = n>>3, i = (n>>1)&3, c = n&1); lane (g,l15) sources
    // row (wm*64 + i*16 + l15), k-chunk c*32 + g*8.
    long aoff[4], boff[4];
    #pragma unroll
    for (int s = 0; s < 4; s++) {
        int n  = wid * 4 + s;
        int rr = (n >> 3) * 64 + ((n >> 1) & 3) * 16 + l15;
        int cc = (n & 1) * 32 + g * 8;
        aoff[s] = (m0 + rr) * (long)K + cc;
        boff[s] = (n0 + rr) * (long)K + cc;
    }

    for (int k0 = 0; k0 < K; k0 += 64) {
        #pragma unroll
        for (int s = 0; s < 4; s++) {
            gl_lds16(A  + aoff[s] + k0, &As[(wid * 4 + s) * 512]);
            gl_lds16(Bt + boff[s] + k0, &Bs[(wid * 4 + s) * 512]);
        }
        __syncthreads();

        bf16x8 af[4][2], bfr[4][2];
        #pragma unroll
        for (int i = 0; i < 4; i++)
            #pragma unroll
            for (int c = 0; c < 2; c++)
                af[i][c] = *(const bf16x8*)&As[(wm * 8 + i * 2 + c) * 512 + lane * 8];
        #pragma unroll
        for (int j = 0; j < 4; j++)
            #pragma unroll
            for (int c = 0; c < 2; c++)
                bfr[j][c] = *(const bf16x8*)&Bs[(wn * 8 + j * 2 + c) * 512 + lane * 8];

        #pragma unroll
        for (int c = 0; c < 2; c++)
            #pragma unroll
            for (int i = 0; i < 4; i++)
                #pragma unroll
                for (int j = 0; j < 4; j++)
                    acc[i][j] = __builtin_amdgcn_mfma_f32_16x16x32_bf16(af[i][c], bfr[j][c], acc[i][j], 0, 0, 0);

        __syncthreads();
    }

    // epilogue: D[m = (lane>>4)*4 + reg][n = lane&15]
    #pragma unroll
    for (int j = 0; j < 4; j++) {
        int n = (int)n0 + wn * 64 + j * 16 + l15;
        float bb = bias[n];
        #pragma unroll
        for (int i = 0; i < 4; i++) {
            int mrow = (int)m0 + wm * 64 + i * 16 + g * 4;
            if (MODE == 1) {
                #pragma unroll
                for (int r = 0; r < 4; r++)
                    fout[(long)(mrow + r) * 1024 + n] = acc[i][j][r] + bb;
            } else {
                if (n < 1024) {
                    const float QS = 0.125f * 1.44269504088896f;   // log2e/sqrt(dk)
                    #pragma unroll
                    for (int r = 0; r < 4; r++)
                        qo[(long)(mrow + r) * 1024 + n] = f2bf((acc[i][j][r] + bb) * QS);
                } else if (n < 2048) {
                    #pragma unroll
                    for (int r = 0; r < 4; r++)
                        ko[(long)(mrow + r) * 1024 + (n - 1024)] = f2bf(acc[i][j][r] + bb);
                } else {
                    int c = n - 2048, h = c >> 6, d = c & 63;
                    int b = mrow >> 11, t = mrow & 2047;
                    s16x4 pk;
                    #pragma unroll
                    for (int r = 0; r < 4; r++) pk[r] = f2bf(acc[i][j][r] + bb);
                    *(s16x4*)&vt[((long)((b * 16 + h) * 64 + d)) * 2048 + t] = pk;
                }
            }
        }
    }
}

// ---------------------------------------------------------------- flash attention
// grid: (TSEQ/128, BATCH*HEADS), block 256 = 4 waves x 32 queries.
// This rev: (1) fragment-major K/V LDS (8 x 1KiB blocks, block = jt*2+c) ->
// staging linear + fragment reads contiguous => zero bank conflicts;
// (2) P transpose in-register via permlane32/16_swap instead of the plds LDS
// round-trip (prior profile: 3.1M conflict cycles, ~40% of LDS time).
__global__ __launch_bounds__(256) void flash_attn_kernel(
    const short* __restrict__ qb, const short* __restrict__ kb,
    const short* __restrict__ vt, short* __restrict__ ob)
{
    __shared__ short Ks[2][8 * 512];   // [buf][block jt*2+c][lane*8]
    __shared__ short Vs[2][8 * 512];

    int tid = threadIdx.x, wid = tid >> 6, lane = tid & 63;
    int g = lane >> 4, l15 = lane & 15;
    int bh = blockIdx.y, b = bh >> 4, h = bh & 15;
    int q0w = blockIdx.x * 128 + wid * 32;
    long qrow = (long)b * TSEQ + q0w;

    bf16x8 qf[2][2];
    #pragma unroll
    for (int qg = 0; qg < 2; qg++)
        #pragma unroll
        for (int c = 0; c < 2; c++)
            qf[qg][c] = *(const bf16x8*)&qb[(qrow + qg * 16 + l15) * 1024 + h * 64 + c * 32 + g * 8];

    bf16x8 ones;
    #pragma unroll
    for (int j = 0; j < 8; j++) ones[j] = (short)0x3F80;   // bf16 1.0

    f32x4 oacc[2][4], lacc[2];
    #pragma unroll
    for (int qg = 0; qg < 2; qg++) {
        lacc[qg] = (f32x4){0.f, 0.f, 0.f, 0.f};
        #pragma unroll
        for (int jt = 0; jt < 4; jt++) oacc[qg][jt] = (f32x4){0.f, 0.f, 0.f, 0.f};
    }

    const short* kg = kb + ((long)b * TSEQ) * 1024 + h * 64;   // + key*1024 + d
    const short* vg = vt + ((long)bh * 64) * 2048;             // + d*2048 + key

    // wave wid stages fragment blocks (jt=wid, c=0|1) of K and V.
    // K block lane (g,l15): row kt*64 + wid*16 + l15, d-chunk c*32 + g*8
    // V block lane (g,l15): d-row wid*16 + l15, key-chunk kt*64 + c*32 + g*8
    int kO = (wid * 16 + l15) * 1024 + g * 8;
    int vO = (wid * 16 + l15) * 2048 + g * 8;
    short* kd0 = &Ks[0][(wid * 2 + 0) * 512];
    short* kd1 = &Ks[0][(wid * 2 + 1) * 512];
    short* vd0 = &Vs[0][(wid * 2 + 0) * 512];
    short* vd1 = &Vs[0][(wid * 2 + 1) * 512];

    #define STAGE(buf, kt)                                                      \
        gl_lds16(kg + (long)(kt) * 65536 + kO,      kd0 + (buf) * 4096);        \
        gl_lds16(kg + (long)(kt) * 65536 + kO + 32, kd1 + (buf) * 4096);        \
        gl_lds16(vg + (long)(kt) * 64 + vO,         vd0 + (buf) * 4096);        \
        gl_lds16(vg + (long)(kt) * 64 + vO + 32,    vd1 + (buf) * 4096);

    #define BODY(cur, nxt, kt, do_pref)                                                  \
    {                                                                                    \
        if (do_pref) { STAGE(nxt, (kt) + 1) }                                            \
        bf16x8 kf[4][2], vf[4][2];                                                       \
        _Pragma("unroll")                                                                \
        for (int jt = 0; jt < 4; jt++)                                                   \
            _Pragma("unroll")                                                            \
            for (int c = 0; c < 2; c++) {                                                \
                kf[jt][c] = *(const bf16x8*)&Ks[cur][(jt * 2 + c) * 512 + lane * 8];     \
                vf[jt][c] = *(const bf16x8*)&Vs[cur][(jt * 2 + c) * 512 + lane * 8];     \
            }                                                                            \
        _Pragma("unroll")                                                                \
        for (int qg = 0; qg < 2; qg++) {                                                 \
            f32x4 s[4];                                                                  \
            _Pragma("unroll")                                                            \
            for (int jt = 0; jt < 4; jt++) {                                             \
                f32x4 t = (f32x4){0.f, 0.f, 0.f, 0.f};                                   \
                t = __builtin_amdgcn_mfma_f32_16x16x32_bf16(kf[jt][0], qf[qg][0], t, 0, 0, 0); \
                t = __builtin_amdgcn_mfma_f32_16x16x32_bf16(kf[jt][1], qf[qg][1], t, 0, 0, 0); \
                s[jt] = t;                                                               \
            }                                                                            \
            /* lane (g,l15) holds P[keys jt*16+g*4+r][q=l15]; pack + permlane to */      \
            /* A-frag layout: lane (g,l15) = P[q=l15][keys g*8..g*8+7] per 32-chunk */   \
            unsigned up[4][2];                                                           \
            _Pragma("unroll")                                                            \
            for (int jt = 0; jt < 4; jt++) {                                             \
                float p0 = __builtin_amdgcn_exp2f(s[jt][0]);                             \
                float p1 = __builtin_amdgcn_exp2f(s[jt][1]);                             \
                float p2 = __builtin_amdgcn_exp2f(s[jt][2]);                             \
                float p3 = __builtin_amdgcn_exp2f(s[jt][3]);                             \
                up[jt][0] = pk_bf16_rn(p0, p1);                                          \
                up[jt][1] = pk_bf16_rn(p2, p3);                                          \
            }                                                                            \
            _Pragma("unroll")                                                            \
            for (int hh = 0; hh < 2; hh++) {                                             \
                pl_swap(up[0][hh], up[1][hh]);                                           \
                pl_swap(up[2][hh], up[3][hh]);                                           \
            }                                                                            \
            bf16x8 pA0 = __builtin_bit_cast(bf16x8, (u32x4){up[0][0], up[0][1], up[1][0], up[1][1]}); \
            bf16x8 pA1 = __builtin_bit_cast(bf16x8, (u32x4){up[2][0], up[2][1], up[3][0], up[3][1]}); \
            lacc[qg] = __builtin_amdgcn_mfma_f32_16x16x32_bf16(pA0, ones, lacc[qg], 0, 0, 0); \
            lacc[qg] = __builtin_amdgcn_mfma_f32_16x16x32_bf16(pA1, ones, lacc[qg], 0, 0, 0); \
            _Pragma("unroll")                                                            \
            for (int jt = 0; jt < 4; jt++) {                                             \
                oacc[qg][jt] = __builtin_amdgcn_mfma_f32_16x16x32_bf16(pA0, vf[jt][0], oacc[qg][jt], 0, 0, 0); \
                oacc[qg][jt] = __builtin_amdgcn_mfma_f32_16x16x32_bf16(pA1, vf[jt][1], oacc[qg][jt], 0, 0, 0); \
            }                                                                            \
        }                                                                                \
        __syncthreads();                                                                 \
    }

    STAGE(0, 0)
    __syncthreads();

    for (int kt = 0; kt < TSEQ / 64; kt += 2) {
        BODY(0, 1, kt, 1)
        BODY(1, 0, kt + 1, (kt + 2 < TSEQ / 64))
    }
    #undef BODY
    #undef STAGE

    // oacc/lacc C-layout: row = q_local = g*4+r, col = l15. lacc columns are all
    // identical (B=ones), so the denominator for row r is lacc[qg][r] in-lane.
    #pragma unroll
    for (int qg = 0; qg < 2; qg++)
        #pragma unroll
        for (int r = 0; r < 4; r++) {
            float inv = 1.f / lacc[qg][r];
            long row = qrow + qg * 16 + g * 4 + r;
            #pragma unroll
            for (int jt = 0; jt < 4; jt++)
                ob[row * 1024 + h * 64 + jt * 16 + l15] = f2bf(oacc[qg][jt][r] * inv);
        }
}

// ---------------------------------------------------------------- launcher
extern "C" void kernel_launch(void* const* d_in, const int* in_sizes, int n_in,
                              void* d_out, int out_size, void* d_ws, size_t ws_size,
                              hipStream_t stream)
{
    const float* x    = (const float*)d_in[0];
    const float* Wqkv = (const float*)d_in[1];
    const float* bqkv = (const float*)d_in[2];
    const float* Wout = (const float*)d_in[3];
    const float* bout = (const float*)d_in[4];
    float* out = (float*)d_out;

    char* ws = (char*)d_ws;
    const size_t SZ_TOKD = (size_t)NTOK * 1024 * sizeof(short);   // 8 MB
    short* xb    = (short*)ws;                 ws += SZ_TOKD;
    short* wqkvt = (short*)ws;                 ws += (size_t)3072 * 1024 * sizeof(short);
    short* woutt = (short*)ws;                 ws += (size_t)1024 * 1024 * sizeof(short);
    short* qb    = (short*)ws;                 ws += SZ_TOKD;
    short* kb    = (short*)ws;                 ws += SZ_TOKD;
    short* vt    = (short*)ws;                 ws += SZ_TOKD;
    short* ob    = (short*)ws;                 ws += SZ_TOKD;
    if ((size_t)(ws - (char*)d_ws) > ws_size) return;   // workspace too small

    prep_kernel<<<8192, 256, 0, stream>>>(x, Wqkv, Wout, xb, wqkvt, woutt);

    gemm_bf16_kernel<0><<<dim3(NTOK / 128, 3072 / 128), 256, 0, stream>>>(
        xb, wqkvt, bqkv, qb, kb, vt, nullptr);

    flash_attn_kernel<<<dim3(TSEQ / 128, BATCH * HEADS), 256, 0, stream>>>(qb, kb, vt, ob);

    gemm_bf16_kernel<1><<<dim3(NTOK / 128, 1024 / 128), 256, 0, stream>>>(
        ob, woutt, bout, nullptr, nullptr, nullptr, out);
}

// Round 2
// 185.871 us; speedup vs baseline: 1.2331x; 1.2331x over previous
//
#include <hip/hip_runtime.h>

#define D_MODEL 1024
#define HEADS   16
#define DK      64
#define BATCH   2
#define TSEQ    2048
#define NTOK    (BATCH * TSEQ)   // 4096

typedef __attribute__((ext_vector_type(8))) short bf16x8;
typedef __attribute__((ext_vector_type(4))) short s16x4;
typedef __attribute__((ext_vector_type(4))) float f32x4;
typedef __attribute__((ext_vector_type(2))) unsigned u32x2;
typedef __attribute__((ext_vector_type(4))) unsigned u32x4;

__device__ __forceinline__ short f2bf(float f) {
    union { float f; unsigned u; } a;
    a.f = f;
    unsigned r = a.u + 0x7FFFu + ((a.u >> 16) & 1u);
    return (short)(r >> 16);
}
// pack two non-negative floats to bf16x2 (round-to-nearest, ties away)
__device__ __forceinline__ unsigned pk_bf16_rn(float a, float b) {
    union { float f; unsigned u; } x, y;
    x.f = a; y.f = b;
    return __builtin_amdgcn_perm(y.u + 0x8000u, x.u + 0x8000u, 0x07060302u);
}

// async global->LDS, 16B per lane. LDS dest = wave-uniform base + lane*16.
__device__ __forceinline__ void gl_lds16(const void* g, void* l) {
    __builtin_amdgcn_global_load_lds(
        (const __attribute__((address_space(1))) unsigned int*)(unsigned long long)g,
        (__attribute__((address_space(3))) unsigned int*)(unsigned int)(unsigned long long)l,
        16, 0, 0);
}

// P-fragment redistribution: permlane32_swap + permlane16_swap pair.
// after pl_swap(a=R[b], b=R[b+1]) (b in {0,2}):
//   a = fragment word for source-parity p=0, b = word for p=1
__device__ __forceinline__ void pl_swap(unsigned& a, unsigned& b) {
    u32x2 r32 = __builtin_amdgcn_permlane32_swap(a, b, false, false);
    u32x2 r16 = __builtin_amdgcn_permlane16_swap(r32[0], r32[1], false, false);
    a = r16[0]; b = r16[1];
}

// ------------------------------------------------- fused prep: transposes + cvt
__global__ __launch_bounds__(256) void prep_kernel(
    const float* __restrict__ x, const float* __restrict__ Wqkv,
    const float* __restrict__ Wout,
    short* __restrict__ xb, short* __restrict__ wqkvt, short* __restrict__ woutt)
{
    int bx = blockIdx.x;
    if (bx < 4096) {
        __shared__ float tile[32][33];
        const float* in; short* out; int N, n0, k0;
        if (bx < 3072) { in = Wqkv; out = wqkvt; N = 3072; n0 = (bx % 96) * 32; k0 = (bx / 96) * 32; }
        else { int t2 = bx - 3072; in = Wout; out = woutt; N = 1024; n0 = (t2 & 31) * 32; k0 = (t2 >> 5) * 32; }
        int tx = threadIdx.x & 31, ty = threadIdx.x >> 5;
        #pragma unroll
        for (int i = 0; i < 32; i += 8)
            tile[ty + i][tx] = in[(long)(k0 + ty + i) * N + n0 + tx];
        __syncthreads();
        #pragma unroll
        for (int i = 0; i < 32; i += 8)
            out[(long)(n0 + ty + i) * 1024 + k0 + tx] = f2bf(tile[tx][ty + i]);
    } else {
        long i = ((long)(bx - 4096) * 256 + threadIdx.x) * 4;
        float4 v = *(const float4*)&x[i];
        s16x4 o;
        o[0] = f2bf(v.x); o[1] = f2bf(v.y); o[2] = f2bf(v.z); o[3] = f2bf(v.w);
        *(s16x4*)&xb[i] = o;
    }
}

// ---------------------------------------------------------------- bf16 MFMA GEMM
// m97-style (round-0 verified): global_load_lds width-16 staging with pre-swizzled
// global source (contiguous 128B runs), row-major LDS with XOR chunk layout
// (~2-way = free fragment reads), 128xBN tiles, 2 barriers per K-step.
// MODE 0: BN=128. QKV epilogue -> q (pre-scaled log2e/8), k, vt[(b*16+h)*64+d][2048]
// MODE 1: BN=64 (grid 32x16 = 512 blocks = 2 blocks/CU for latency hiding) -> fp32 out
template<int MODE>
__global__ __launch_bounds__(256) void gemm_bf16_kernel(
    const short* __restrict__ A, const short* __restrict__ Bt,
    const float* __restrict__ bias,
    short* __restrict__ qo, short* __restrict__ ko, short* __restrict__ vt,
    float* __restrict__ fout)
{
    const int K = 1024;
    constexpr int BN = (MODE == 1) ? 64 : 128;
    constexpr int NJ = BN / 32;            // j-tiles per wave (4 or 2)
    constexpr int SB = BN / 32;            // B staging instrs per wave (4 or 2)

    __shared__ short As[128 * 64];         // [row*64 + (chunk^(row&7))*8]
    __shared__ short Bs[BN * 64];

    int tid  = threadIdx.x;
    int wid  = tid >> 6, lane = tid & 63;
    int wm   = wid >> 1, wn   = wid & 1;
    int g    = lane >> 4, l15 = lane & 15;
    int swzr = l15 & 7;
    long m0  = (long)blockIdx.x * 128;
    long n0  = (long)blockIdx.y * BN;

    f32x4 acc[4][NJ];
    #pragma unroll
    for (int i = 0; i < 4; i++)
        #pragma unroll
        for (int j = 0; j < NJ; j++)
            acc[i][j] = (f32x4){0.f, 0.f, 0.f, 0.f};

    int srow  = wid * 32 + (lane >> 3);
    int srowb = wid * (BN / 4) + (lane >> 3);
    int sch   = ((lane & 7) ^ ((lane >> 3) & 7)) * 8;   // shorts
    const short* Abase = A  + (m0 + srow)  * K + sch;
    const short* Bbase = Bt + (n0 + srowb) * K + sch;
    short* adst = &As[wid * 32 * 64];
    short* bdst = &Bs[wid * (BN / 4) * 64];

    for (int k0 = 0; k0 < K; k0 += 64) {
        #pragma unroll
        for (int s = 0; s < 4; s++)
            gl_lds16(Abase + (long)s * 8 * K + k0, adst + s * 8 * 64);
        #pragma unroll
        for (int s = 0; s < SB; s++)
            gl_lds16(Bbase + (long)s * 8 * K + k0, bdst + s * 8 * 64);
        __syncthreads();

        bf16x8 af[4][2], bfr[NJ][2];
        #pragma unroll
        for (int i = 0; i < 4; i++)
            #pragma unroll
            for (int c = 0; c < 2; c++)
                af[i][c] = *(const bf16x8*)&As[(wm * 64 + i * 16 + l15) * 64 + (((c * 4 + g) ^ swzr) << 3)];
        #pragma unroll
        for (int j = 0; j < NJ; j++)
            #pragma unroll
            for (int c = 0; c < 2; c++)
                bfr[j][c] = *(const bf16x8*)&Bs[(wn * (BN / 2) + j * 16 + l15) * 64 + (((c * 4 + g) ^ swzr) << 3)];

        #pragma unroll
        for (int c = 0; c < 2; c++)
            #pragma unroll
            for (int i = 0; i < 4; i++)
                #pragma unroll
                for (int j = 0; j < NJ; j++)
                    acc[i][j] = __builtin_amdgcn_mfma_f32_16x16x32_bf16(af[i][c], bfr[j][c], acc[i][j], 0, 0, 0);

        __syncthreads();
    }

    // epilogue: D[m = (lane>>4)*4 + reg][n = lane&15]
    #pragma unroll
    for (int j = 0; j < NJ; j++) {
        int n = (int)n0 + wn * (BN / 2) + j * 16 + l15;
        float bb = bias[n];
        #pragma unroll
        for (int i = 0; i < 4; i++) {
            int mrow = (int)m0 + wm * 64 + i * 16 + g * 4;
            if (MODE == 1) {
                #pragma unroll
                for (int r = 0; r < 4; r++)
                    fout[(long)(mrow + r) * 1024 + n] = acc[i][j][r] + bb;
            } else {
                if (n < 1024) {
                    const float QS = 0.125f * 1.44269504088896f;   // log2e/sqrt(dk)
                    #pragma unroll
                    for (int r = 0; r < 4; r++)
                        qo[(long)(mrow + r) * 1024 + n] = f2bf((acc[i][j][r] + bb) * QS);
                } else if (n < 2048) {
                    #pragma unroll
                    for (int r = 0; r < 4; r++)
                        ko[(long)(mrow + r) * 1024 + (n - 1024)] = f2bf(acc[i][j][r] + bb);
                } else {
                    int c = n - 2048, h = c >> 6, d = c & 63;
                    int b = mrow >> 11, t = mrow & 2047;
                    s16x4 pk;
                    #pragma unroll
                    for (int r = 0; r < 4; r++) pk[r] = f2bf(acc[i][j][r] + bb);
                    *(s16x4*)&vt[((long)((b * 16 + h) * 64 + d)) * 2048 + t] = pk;
                }
            }
        }
    }
}

// ---------------------------------------------------------------- flash attention
// grid: (TSEQ/128, BATCH*HEADS), block 256 = 4 waves x 32 queries.
// Round-0 K/V staging (contiguous 128B global runs + XOR-chunk LDS, ~2-way free
// reads) + round-1 in-register P transpose via permlane32/16_swap (replaces the
// plds LDS round-trip that carried the 3.1M conflict cycles). LDS 51 -> 32 KB.
__global__ __launch_bounds__(256) void flash_attn_kernel(
    const short* __restrict__ qb, const short* __restrict__ kb,
    const short* __restrict__ vt, short* __restrict__ ob)
{
    __shared__ short Ks[2][64 * 64];          // [buf][key*64 + swz(chunk)*8]
    __shared__ short Vs[2][64 * 64];          // [buf][d*64 + swz(chunk)*8]

    int tid = threadIdx.x, wid = tid >> 6, lane = tid & 63;
    int g = lane >> 4, l15 = lane & 15;
    int swzr = l15 & 7;
    int bh = blockIdx.y, b = bh >> 4, h = bh & 15;
    int q0w = blockIdx.x * 128 + wid * 32;
    long qrow = (long)b * TSEQ + q0w;

    bf16x8 qf[2][2];
    #pragma unroll
    for (int qg = 0; qg < 2; qg++)
        #pragma unroll
        for (int c = 0; c < 2; c++)
            qf[qg][c] = *(const bf16x8*)&qb[(qrow + qg * 16 + l15) * 1024 + h * 64 + c * 32 + g * 8];

    bf16x8 ones;
    #pragma unroll
    for (int j = 0; j < 8; j++) ones[j] = (short)0x3F80;   // bf16 1.0

    f32x4 oacc[2][4], lacc[2];
    #pragma unroll
    for (int qg = 0; qg < 2; qg++) {
        lacc[qg] = (f32x4){0.f, 0.f, 0.f, 0.f};
        #pragma unroll
        for (int jt = 0; jt < 4; jt++) oacc[qg][jt] = (f32x4){0.f, 0.f, 0.f, 0.f};
    }

    const short* kg = kb + ((long)b * TSEQ) * 1024 + h * 64;   // + key*1024 + d
    const short* vg = vt + ((long)bh * 64) * 2048;             // + d*2048 + key

    int ch = (((lane & 7) ^ ((lane >> 3) & 7))) * 8;   // swizzled global chunk offset
    int r0 = wid * 16 + (lane >> 3);
    int r1 = r0 + 8;
    short* kdst0 = &Ks[0][(wid * 2 + 0) * 512];
    short* kdst1 = &Ks[0][(wid * 2 + 1) * 512];
    short* vdst0 = &Vs[0][(wid * 2 + 0) * 512];
    short* vdst1 = &Vs[0][(wid * 2 + 1) * 512];

    #define STAGE(buf, kt)                                                        \
        gl_lds16(kg + (long)((kt) * 64 + r0) * 1024 + ch, kdst0 + (buf) * 4096);  \
        gl_lds16(kg + (long)((kt) * 64 + r1) * 1024 + ch, kdst1 + (buf) * 4096);  \
        gl_lds16(vg + (long)r0 * 2048 + (kt) * 64 + ch,   vdst0 + (buf) * 4096);  \
        gl_lds16(vg + (long)r1 * 2048 + (kt) * 64 + ch,   vdst1 + (buf) * 4096);

    #define BODY(cur, nxt, kt, do_pref)                                                  \
    {                                                                                    \
        if (do_pref) { STAGE(nxt, (kt) + 1) }                                            \
        bf16x8 kf[4][2], vf[4][2];                                                       \
        _Pragma("unroll")                                                                \
        for (int jt = 0; jt < 4; jt++)                                                   \
            _Pragma("unroll")                                                            \
            for (int c = 0; c < 2; c++) {                                                \
                int off = (jt * 16 + l15) * 64 + (((c * 4 + g) ^ swzr) << 3);            \
                kf[jt][c] = *(const bf16x8*)&Ks[cur][off];                               \
                vf[jt][c] = *(const bf16x8*)&Vs[cur][off];                               \
            }                                                                            \
        _Pragma("unroll")                                                                \
        for (int qg = 0; qg < 2; qg++) {                                                 \
            f32x4 s[4];                                                                  \
            _Pragma("unroll")                                                            \
            for (int jt = 0; jt < 4; jt++) {                                             \
                f32x4 t = (f32x4){0.f, 0.f, 0.f, 0.f};                                   \
                t = __builtin_amdgcn_mfma_f32_16x16x32_bf16(kf[jt][0], qf[qg][0], t, 0, 0, 0); \
                t = __builtin_amdgcn_mfma_f32_16x16x32_bf16(kf[jt][1], qf[qg][1], t, 0, 0, 0); \
                s[jt] = t;                                                               \
            }                                                                            \
            /* lane (g,l15) holds P[keys jt*16+g*4+r][q=l15]; pack + permlane to */      \
            /* A-frag layout: lane (g,l15) = P[q=l15][keys g*8..g*8+7] per 32-chunk */   \
            unsigned up[4][2];                                                           \
            _Pragma("unroll")                                                            \
            for (int jt = 0; jt < 4; jt++) {                                             \
                float p0 = __builtin_amdgcn_exp2f(s[jt][0]);                             \
                float p1 = __builtin_amdgcn_exp2f(s[jt][1]);                             \
                float p2 = __builtin_amdgcn_exp2f(s[jt][2]);                             \
                float p3 = __builtin_amdgcn_exp2f(s[jt][3]);                             \
                up[jt][0] = pk_bf16_rn(p0, p1);                                          \
                up[jt][1] = pk_bf16_rn(p2, p3);                                          \
            }                                                                            \
            _Pragma("unroll")                                                            \
            for (int hh = 0; hh < 2; hh++) {                                             \
                pl_swap(up[0][hh], up[1][hh]);                                           \
                pl_swap(up[2][hh], up[3][hh]);                                           \
            }                                                                            \
            bf16x8 pA0 = __builtin_bit_cast(bf16x8, (u32x4){up[0][0], up[0][1], up[1][0], up[1][1]}); \
            bf16x8 pA1 = __builtin_bit_cast(bf16x8, (u32x4){up[2][0], up[2][1], up[3][0], up[3][1]}); \
            lacc[qg] = __builtin_amdgcn_mfma_f32_16x16x32_bf16(pA0, ones, lacc[qg], 0, 0, 0); \
            lacc[qg] = __builtin_amdgcn_mfma_f32_16x16x32_bf16(pA1, ones, lacc[qg], 0, 0, 0); \
            _Pragma("unroll")                                                            \
            for (int jt = 0; jt < 4; jt++) {                                             \
                oacc[qg][jt] = __builtin_amdgcn_mfma_f32_16x16x32_bf16(pA0, vf[jt][0], oacc[qg][jt], 0, 0, 0); \
                oacc[qg][jt] = __builtin_amdgcn_mfma_f32_16x16x32_bf16(pA1, vf[jt][1], oacc[qg][jt], 0, 0, 0); \
            }                                                                            \
        }                                                                                \
        __syncthreads();                                                                 \
    }

    STAGE(0, 0)
    __syncthreads();

    for (int kt = 0; kt < TSEQ / 64; kt += 2) {
        BODY(0, 1, kt, 1)
        BODY(1, 0, kt + 1, (kt + 2 < TSEQ / 64))
    }
    #undef BODY
    #undef STAGE

    // oacc/lacc C-layout: row = q_local = g*4+r, col = l15. lacc columns are all
    // identical (B=ones), so the denominator for row r is lacc[qg][r] in-lane.
    #pragma unroll
    for (int qg = 0; qg < 2; qg++)
        #pragma unroll
        for (int r = 0; r < 4; r++) {
            float inv = 1.f / lacc[qg][r];
            long row = qrow + qg * 16 + g * 4 + r;
            #pragma unroll
            for (int jt = 0; jt < 4; jt++)
                ob[row * 1024 + h * 64 + jt * 16 + l15] = f2bf(oacc[qg][jt][r] * inv);
        }
}

// ---------------------------------------------------------------- launcher
extern "C" void kernel_launch(void* const* d_in, const int* in_sizes, int n_in,
                              void* d_out, int out_size, void* d_ws, size_t ws_size,
                              hipStream_t stream)
{
    const float* x    = (const float*)d_in[0];
    const float* Wqkv = (const float*)d_in[1];
    const float* bqkv = (const float*)d_in[2];
    const float* Wout = (const float*)d_in[3];
    const float* bout = (const float*)d_in[4];
    float* out = (float*)d_out;

    char* ws = (char*)d_ws;
    const size_t SZ_TOKD = (size_t)NTOK * 1024 * sizeof(short);   // 8 MB
    short* xb    = (short*)ws;                 ws += SZ_TOKD;
    short* wqkvt = (short*)ws;                 ws += (size_t)3072 * 1024 * sizeof(short);
    short* woutt = (short*)ws;                 ws += (size_t)1024 * 1024 * sizeof(short);
    short* qb    = (short*)ws;                 ws += SZ_TOKD;
    short* kb    = (short*)ws;                 ws += SZ_TOKD;
    short* vt    = (short*)ws;                 ws += SZ_TOKD;
    short* ob    = (short*)ws;                 ws += SZ_TOKD;
    if ((size_t)(ws - (char*)d_ws) > ws_size) return;   // workspace too small

    prep_kernel<<<8192, 256, 0, stream>>>(x, Wqkv, Wout, xb, wqkvt, woutt);

    gemm_bf16_kernel<0><<<dim3(NTOK / 128, 3072 / 128), 256, 0, stream>>>(
        xb, wqkvt, bqkv, qb, kb, vt, nullptr);

    flash_attn_kernel<<<dim3(TSEQ / 128, BATCH * HEADS), 256, 0, stream>>>(qb, kb, vt, ob);

    gemm_bf16_kernel<1><<<dim3(NTOK / 128, 1024 / 64), 256, 0, stream>>>(
        ob, woutt, bout, nullptr, nullptr, nullptr, out);
}

// Round 3
// 185.241 us; speedup vs baseline: 1.2373x; 1.0034x over previous
//
#include <hip/hip_runtime.h>

#define D_MODEL 1024
#define HEADS   16
#define DK      64
#define BATCH   2
#define TSEQ    2048
#define NTOK    (BATCH * TSEQ)   // 4096

typedef __attribute__((ext_vector_type(8))) short bf16x8;
typedef __attribute__((ext_vector_type(4))) short s16x4;
typedef __attribute__((ext_vector_type(4))) float f32x4;
typedef __attribute__((ext_vector_type(2))) unsigned u32x2;
typedef __attribute__((ext_vector_type(4))) unsigned u32x4;

__device__ __forceinline__ short f2bf(float f) {
    union { float f; unsigned u; } a;
    a.f = f;
    unsigned r = a.u + 0x7FFFu + ((a.u >> 16) & 1u);
    return (short)(r >> 16);
}
// one-instruction packed f32->bf16x2 (RNE): lo = bf16(a), hi = bf16(b)
__device__ __forceinline__ unsigned cvt_pk_bf16(float a, float b) {
    unsigned r;
    asm("v_cvt_pk_bf16_f32 %0, %1, %2" : "=v"(r) : "v"(a), "v"(b));
    return r;
}

// async global->LDS, 16B per lane. LDS dest = wave-uniform base + lane*16.
__device__ __forceinline__ void gl_lds16(const void* g, void* l) {
    __builtin_amdgcn_global_load_lds(
        (const __attribute__((address_space(1))) unsigned int*)(unsigned long long)g,
        (__attribute__((address_space(3))) unsigned int*)(unsigned int)(unsigned long long)l,
        16, 0, 0);
}

// P-fragment redistribution: permlane32_swap + permlane16_swap pair.
// after pl_swap(a=R[b], b=R[b+1]) (b in {0,2}):
//   a = fragment word for source-parity p=0, b = word for p=1
__device__ __forceinline__ void pl_swap(unsigned& a, unsigned& b) {
    u32x2 r32 = __builtin_amdgcn_permlane32_swap(a, b, false, false);
    u32x2 r16 = __builtin_amdgcn_permlane16_swap(r32[0], r32[1], false, false);
    a = r16[0]; b = r16[1];
}

// ------------------------------------------------- fused prep: transposes + cvt
__global__ __launch_bounds__(256) void prep_kernel(
    const float* __restrict__ x, const float* __restrict__ Wqkv,
    const float* __restrict__ Wout,
    short* __restrict__ xb, short* __restrict__ wqkvt, short* __restrict__ woutt)
{
    int bx = blockIdx.x;
    if (bx < 4096) {
        __shared__ float tile[32][33];
        const float* in; short* out; int N, n0, k0;
        if (bx < 3072) { in = Wqkv; out = wqkvt; N = 3072; n0 = (bx % 96) * 32; k0 = (bx / 96) * 32; }
        else { int t2 = bx - 3072; in = Wout; out = woutt; N = 1024; n0 = (t2 & 31) * 32; k0 = (t2 >> 5) * 32; }
        int tx = threadIdx.x & 31, ty = threadIdx.x >> 5;
        #pragma unroll
        for (int i = 0; i < 32; i += 8)
            tile[ty + i][tx] = in[(long)(k0 + ty + i) * N + n0 + tx];
        __syncthreads();
        #pragma unroll
        for (int i = 0; i < 32; i += 8)
            out[(long)(n0 + ty + i) * 1024 + k0 + tx] = f2bf(tile[tx][ty + i]);
    } else {
        long i = ((long)(bx - 4096) * 256 + threadIdx.x) * 4;
        float4 v = *(const float4*)&x[i];
        s16x4 o;
        o[0] = f2bf(v.x); o[1] = f2bf(v.y); o[2] = f2bf(v.z); o[3] = f2bf(v.w);
        *(s16x4*)&xb[i] = o;
    }
}

// ---------------------------------------------------------------- bf16 MFMA GEMM
// m97-style (round-0 verified): global_load_lds width-16 staging with pre-swizzled
// global source (contiguous 128B runs), row-major LDS with XOR chunk layout
// (~2-way = free fragment reads), 128xBN tiles, 2 barriers per K-step.
// MODE 0: BN=128. QKV epilogue -> q (pre-scaled log2e/8), k, vt[(b*16+h)*64+d][2048]
// MODE 1: BN=64 (grid 32x16 = 512 blocks = 2 blocks/CU for latency hiding) -> fp32 out
template<int MODE>
__global__ __launch_bounds__(256) void gemm_bf16_kernel(
    const short* __restrict__ A, const short* __restrict__ Bt,
    const float* __restrict__ bias,
    short* __restrict__ qo, short* __restrict__ ko, short* __restrict__ vt,
    float* __restrict__ fout)
{
    const int K = 1024;
    constexpr int BN = (MODE == 1) ? 64 : 128;
    constexpr int NJ = BN / 32;            // j-tiles per wave (4 or 2)
    constexpr int SB = BN / 32;            // B staging instrs per wave (4 or 2)

    __shared__ short As[128 * 64];         // [row*64 + (chunk^(row&7))*8]
    __shared__ short Bs[BN * 64];

    int tid  = threadIdx.x;
    int wid  = tid >> 6, lane = tid & 63;
    int wm   = wid >> 1, wn   = wid & 1;
    int g    = lane >> 4, l15 = lane & 15;
    int swzr = l15 & 7;
    long m0  = (long)blockIdx.x * 128;
    long n0  = (long)blockIdx.y * BN;

    f32x4 acc[4][NJ];
    #pragma unroll
    for (int i = 0; i < 4; i++)
        #pragma unroll
        for (int j = 0; j < NJ; j++)
            acc[i][j] = (f32x4){0.f, 0.f, 0.f, 0.f};

    int srow  = wid * 32 + (lane >> 3);
    int srowb = wid * (BN / 4) + (lane >> 3);
    int sch   = ((lane & 7) ^ ((lane >> 3) & 7)) * 8;   // shorts
    const short* Abase = A  + (m0 + srow)  * K + sch;
    const short* Bbase = Bt + (n0 + srowb) * K + sch;
    short* adst = &As[wid * 32 * 64];
    short* bdst = &Bs[wid * (BN / 4) * 64];

    for (int k0 = 0; k0 < K; k0 += 64) {
        #pragma unroll
        for (int s = 0; s < 4; s++)
            gl_lds16(Abase + (long)s * 8 * K + k0, adst + s * 8 * 64);
        #pragma unroll
        for (int s = 0; s < SB; s++)
            gl_lds16(Bbase + (long)s * 8 * K + k0, bdst + s * 8 * 64);
        __syncthreads();

        bf16x8 af[4][2], bfr[NJ][2];
        #pragma unroll
        for (int i = 0; i < 4; i++)
            #pragma unroll
            for (int c = 0; c < 2; c++)
                af[i][c] = *(const bf16x8*)&As[(wm * 64 + i * 16 + l15) * 64 + (((c * 4 + g) ^ swzr) << 3)];
        #pragma unroll
        for (int j = 0; j < NJ; j++)
            #pragma unroll
            for (int c = 0; c < 2; c++)
                bfr[j][c] = *(const bf16x8*)&Bs[(wn * (BN / 2) + j * 16 + l15) * 64 + (((c * 4 + g) ^ swzr) << 3)];

        #pragma unroll
        for (int c = 0; c < 2; c++)
            #pragma unroll
            for (int i = 0; i < 4; i++)
                #pragma unroll
                for (int j = 0; j < NJ; j++)
                    acc[i][j] = __builtin_amdgcn_mfma_f32_16x16x32_bf16(af[i][c], bfr[j][c], acc[i][j], 0, 0, 0);

        __syncthreads();
    }

    // epilogue: D[m = (lane>>4)*4 + reg][n = lane&15]
    #pragma unroll
    for (int j = 0; j < NJ; j++) {
        int n = (int)n0 + wn * (BN / 2) + j * 16 + l15;
        float bb = bias[n];
        #pragma unroll
        for (int i = 0; i < 4; i++) {
            int mrow = (int)m0 + wm * 64 + i * 16 + g * 4;
            if (MODE == 1) {
                #pragma unroll
                for (int r = 0; r < 4; r++)
                    fout[(long)(mrow + r) * 1024 + n] = acc[i][j][r] + bb;
            } else {
                if (n < 1024) {
                    const float QS = 0.125f * 1.44269504088896f;   // log2e/sqrt(dk)
                    #pragma unroll
                    for (int r = 0; r < 4; r++)
                        qo[(long)(mrow + r) * 1024 + n] = f2bf((acc[i][j][r] + bb) * QS);
                } else if (n < 2048) {
                    #pragma unroll
                    for (int r = 0; r < 4; r++)
                        ko[(long)(mrow + r) * 1024 + (n - 1024)] = f2bf(acc[i][j][r] + bb);
                } else {
                    int c = n - 2048, h = c >> 6, d = c & 63;
                    int b = mrow >> 11, t = mrow & 2047;
                    s16x4 pk;
                    #pragma unroll
                    for (int r = 0; r < 4; r++) pk[r] = f2bf(acc[i][j][r] + bb);
                    *(s16x4*)&vt[((long)((b * 16 + h) * 64 + d)) * 2048 + t] = pk;
                }
            }
        }
    }
}

// ---------------------------------------------------------------- flash attention
// grid: (TSEQ/64, BATCH*HEADS) = 1024 blocks (4 blocks/CU = 4 waves/SIMD; round-2
// profile showed 2 blocks/CU with VALUBusy 52% = grid-limited latency hiding).
// Block = 4 waves x 16 queries (Q-tile 64). XCD-aware swizzle pins each head's
// 512 KB K/V stream to one XCD's L2. K/V staging + XOR-chunk LDS unchanged
// (conflicts measured 0). P transpose in-register (permlane), pack via
// single-instruction v_cvt_pk_bf16_f32 (was 3 VALU ops per pair).
__global__ __launch_bounds__(256) void flash_attn_kernel(
    const short* __restrict__ qb, const short* __restrict__ kb,
    const short* __restrict__ vt, short* __restrict__ ob)
{
    __shared__ short Ks[2][64 * 64];          // [buf][key*64 + swz(chunk)*8]
    __shared__ short Vs[2][64 * 64];          // [buf][d*64 + swz(chunk)*8]

    int tid = threadIdx.x, wid = tid >> 6, lane = tid & 63;
    int g = lane >> 4, l15 = lane & 15;
    int swzr = l15 & 7;

    // XCD swizzle: 1024 blocks on 8 XCDs; cluster so XCD k owns heads [4k,4k+4)
    // (2 MB K/V working set per XCD L2). Bijective: 1024 % 8 == 0.
    int fid = blockIdx.y * 32 + blockIdx.x;   // linear dispatch id (gridDim.x=32)
    int swb = (fid & 7) * 128 + (fid >> 3);
    int bh  = swb >> 5;                        // 0..31
    int qt  = swb & 31;                        // q-tile 0..31
    int b = bh >> 4, h = bh & 15;
    int q0w = qt * 64 + wid * 16;
    long qrow = (long)b * TSEQ + q0w;

    bf16x8 qf[2];
    #pragma unroll
    for (int c = 0; c < 2; c++)
        qf[c] = *(const bf16x8*)&qb[(qrow + l15) * 1024 + h * 64 + c * 32 + g * 8];

    bf16x8 ones;
    #pragma unroll
    for (int j = 0; j < 8; j++) ones[j] = (short)0x3F80;   // bf16 1.0

    f32x4 oacc[4], lacc;
    lacc = (f32x4){0.f, 0.f, 0.f, 0.f};
    #pragma unroll
    for (int jt = 0; jt < 4; jt++) oacc[jt] = (f32x4){0.f, 0.f, 0.f, 0.f};

    const short* kg = kb + ((long)b * TSEQ) * 1024 + h * 64;   // + key*1024 + d
    const short* vg = vt + ((long)bh * 64) * 2048;             // + d*2048 + key

    int ch = (((lane & 7) ^ ((lane >> 3) & 7))) * 8;   // swizzled global chunk offset
    int r0 = wid * 16 + (lane >> 3);
    int r1 = r0 + 8;
    short* kdst0 = &Ks[0][(wid * 2 + 0) * 512];
    short* kdst1 = &Ks[0][(wid * 2 + 1) * 512];
    short* vdst0 = &Vs[0][(wid * 2 + 0) * 512];
    short* vdst1 = &Vs[0][(wid * 2 + 1) * 512];

    #define STAGE(buf, kt)                                                        \
        gl_lds16(kg + (long)((kt) * 64 + r0) * 1024 + ch, kdst0 + (buf) * 4096);  \
        gl_lds16(kg + (long)((kt) * 64 + r1) * 1024 + ch, kdst1 + (buf) * 4096);  \
        gl_lds16(vg + (long)r0 * 2048 + (kt) * 64 + ch,   vdst0 + (buf) * 4096);  \
        gl_lds16(vg + (long)r1 * 2048 + (kt) * 64 + ch,   vdst1 + (buf) * 4096);

    #define BODY(cur, nxt, kt, do_pref)                                                  \
    {                                                                                    \
        if (do_pref) { STAGE(nxt, (kt) + 1) }                                            \
        bf16x8 kf[4][2], vf[4][2];                                                       \
        _Pragma("unroll")                                                                \
        for (int jt = 0; jt < 4; jt++)                                                   \
            _Pragma("unroll")                                                            \
            for (int c = 0; c < 2; c++) {                                                \
                int off = (jt * 16 + l15) * 64 + (((c * 4 + g) ^ swzr) << 3);            \
                kf[jt][c] = *(const bf16x8*)&Ks[cur][off];                               \
                vf[jt][c] = *(const bf16x8*)&Vs[cur][off];                               \
            }                                                                            \
        f32x4 s[4];                                                                      \
        _Pragma("unroll")                                                                \
        for (int jt = 0; jt < 4; jt++) {                                                 \
            f32x4 t = (f32x4){0.f, 0.f, 0.f, 0.f};                                       \
            t = __builtin_amdgcn_mfma_f32_16x16x32_bf16(kf[jt][0], qf[0], t, 0, 0, 0);   \
            t = __builtin_amdgcn_mfma_f32_16x16x32_bf16(kf[jt][1], qf[1], t, 0, 0, 0);   \
            s[jt] = t;                                                                   \
        }                                                                                \
        /* lane (g,l15) holds P[keys jt*16+g*4+r][q=l15]; pack + permlane to */          \
        /* A-frag layout: lane (g,l15) = P[q=l15][keys g*8..g*8+7] per 32-chunk */       \
        unsigned up[4][2];                                                               \
        _Pragma("unroll")                                                                \
        for (int jt = 0; jt < 4; jt++) {                                                 \
            float p0 = __builtin_amdgcn_exp2f(s[jt][0]);                                 \
            float p1 = __builtin_amdgcn_exp2f(s[jt][1]);                                 \
            float p2 = __builtin_amdgcn_exp2f(s[jt][2]);                                 \
            float p3 = __builtin_amdgcn_exp2f(s[jt][3]);                                 \
            up[jt][0] = cvt_pk_bf16(p0, p1);                                             \
            up[jt][1] = cvt_pk_bf16(p2, p3);                                             \
        }                                                                                \
        _Pragma("unroll")                                                                \
        for (int hh = 0; hh < 2; hh++) {                                                 \
            pl_swap(up[0][hh], up[1][hh]);                                               \
            pl_swap(up[2][hh], up[3][hh]);                                               \
        }                                                                                \
        bf16x8 pA0 = __builtin_bit_cast(bf16x8, (u32x4){up[0][0], up[0][1], up[1][0], up[1][1]}); \
        bf16x8 pA1 = __builtin_bit_cast(bf16x8, (u32x4){up[2][0], up[2][1], up[3][0], up[3][1]}); \
        lacc = __builtin_amdgcn_mfma_f32_16x16x32_bf16(pA0, ones, lacc, 0, 0, 0);        \
        lacc = __builtin_amdgcn_mfma_f32_16x16x32_bf16(pA1, ones, lacc, 0, 0, 0);        \
        _Pragma("unroll")                                                                \
        for (int jt = 0; jt < 4; jt++) {                                                 \
            oacc[jt] = __builtin_amdgcn_mfma_f32_16x16x32_bf16(pA0, vf[jt][0], oacc[jt], 0, 0, 0); \
            oacc[jt] = __builtin_amdgcn_mfma_f32_16x16x32_bf16(pA1, vf[jt][1], oacc[jt], 0, 0, 0); \
        }                                                                                \
        __syncthreads();                                                                 \
    }

    STAGE(0, 0)
    __syncthreads();

    for (int kt = 0; kt < TSEQ / 64; kt += 2) {
        BODY(0, 1, kt, 1)
        BODY(1, 0, kt + 1, (kt + 2 < TSEQ / 64))
    }
    #undef BODY
    #undef STAGE

    // oacc/lacc C-layout: row = q_local = g*4+r, col = l15. lacc columns are all
    // identical (B=ones), so the denominator for row r is lacc[r] in-lane.
    #pragma unroll
    for (int r = 0; r < 4; r++) {
        float inv = 1.f / lacc[r];
        long row = qrow + g * 4 + r;
        #pragma unroll
        for (int jt = 0; jt < 4; jt++)
            ob[row * 1024 + h * 64 + jt * 16 + l15] = f2bf(oacc[jt][r] * inv);
    }
}

// ---------------------------------------------------------------- launcher
extern "C" void kernel_launch(void* const* d_in, const int* in_sizes, int n_in,
                              void* d_out, int out_size, void* d_ws, size_t ws_size,
                              hipStream_t stream)
{
    const float* x    = (const float*)d_in[0];
    const float* Wqkv = (const float*)d_in[1];
    const float* bqkv = (const float*)d_in[2];
    const float* Wout = (const float*)d_in[3];
    const float* bout = (const float*)d_in[4];
    float* out = (float*)d_out;

    char* ws = (char*)d_ws;
    const size_t SZ_TOKD = (size_t)NTOK * 1024 * sizeof(short);   // 8 MB
    short* xb    = (short*)ws;                 ws += SZ_TOKD;
    short* wqkvt = (short*)ws;                 ws += (size_t)3072 * 1024 * sizeof(short);
    short* woutt = (short*)ws;                 ws += (size_t)1024 * 1024 * sizeof(short);
    short* qb    = (short*)ws;                 ws += SZ_TOKD;
    short* kb    = (short*)ws;                 ws += SZ_TOKD;
    short* vt    = (short*)ws;                 ws += SZ_TOKD;
    short* ob    = (short*)ws;                 ws += SZ_TOKD;
    if ((size_t)(ws - (char*)d_ws) > ws_size) return;   // workspace too small

    prep_kernel<<<8192, 256, 0, stream>>>(x, Wqkv, Wout, xb, wqkvt, woutt);

    gemm_bf16_kernel<0><<<dim3(NTOK / 128, 3072 / 128), 256, 0, stream>>>(
        xb, wqkvt, bqkv, qb, kb, vt, nullptr);

    flash_attn_kernel<<<dim3(TSEQ / 64, BATCH * HEADS), 256, 0, stream>>>(qb, kb, vt, ob);

    gemm_bf16_kernel<1><<<dim3(NTOK / 128, 1024 / 64), 256, 0, stream>>>(
        ob, woutt, bout, nullptr, nullptr, nullptr, out);
}

// Round 4
// 173.080 us; speedup vs baseline: 1.3242x; 1.0703x over previous
//
#include <hip/hip_runtime.h>

#define D_MODEL 1024
#define HEADS   16
#define DK      64
#define BATCH   2
#define TSEQ    2048
#define NTOK    (BATCH * TSEQ)   // 4096

typedef __attribute__((ext_vector_type(8))) short bf16x8;
typedef __attribute__((ext_vector_type(4))) short s16x4;
typedef __attribute__((ext_vector_type(4))) float f32x4;
typedef __attribute__((ext_vector_type(2))) unsigned u32x2;
typedef __attribute__((ext_vector_type(4))) unsigned u32x4;

__device__ __forceinline__ short f2bf(float f) {
    union { float f; unsigned u; } a;
    a.f = f;
    unsigned r = a.u + 0x7FFFu + ((a.u >> 16) & 1u);
    return (short)(r >> 16);
}
// one-instruction packed f32->bf16x2 (RNE): lo = bf16(a), hi = bf16(b)
__device__ __forceinline__ unsigned cvt_pk_bf16(float a, float b) {
    unsigned r;
    asm("v_cvt_pk_bf16_f32 %0, %1, %2" : "=v"(r) : "v"(a), "v"(b));
    return r;
}

// async global->LDS, 16B per lane. LDS dest = wave-uniform base + lane*16.
__device__ __forceinline__ void gl_lds16(const void* g, void* l) {
    __builtin_amdgcn_global_load_lds(
        (const __attribute__((address_space(1))) unsigned int*)(unsigned long long)g,
        (__attribute__((address_space(3))) unsigned int*)(unsigned int)(unsigned long long)l,
        16, 0, 0);
}

// P-fragment redistribution: permlane32_swap + permlane16_swap pair.
// after pl_swap(a=R[b], b=R[b+1]) (b in {0,2}):
//   a = fragment word for source-parity p=0, b = word for p=1
__device__ __forceinline__ void pl_swap(unsigned& a, unsigned& b) {
    u32x2 r32 = __builtin_amdgcn_permlane32_swap(a, b, false, false);
    u32x2 r16 = __builtin_amdgcn_permlane16_swap(r32[0], r32[1], false, false);
    a = r16[0]; b = r16[1];
}

// ------------------------------------------------- fused prep: transposes + cvt
__global__ __launch_bounds__(256) void prep_kernel(
    const float* __restrict__ x, const float* __restrict__ Wqkv,
    const float* __restrict__ Wout,
    short* __restrict__ xb, short* __restrict__ wqkvt, short* __restrict__ woutt)
{
    int bx = blockIdx.x;
    if (bx < 4096) {
        __shared__ float tile[32][33];
        const float* in; short* out; int N, n0, k0;
        if (bx < 3072) { in = Wqkv; out = wqkvt; N = 3072; n0 = (bx % 96) * 32; k0 = (bx / 96) * 32; }
        else { int t2 = bx - 3072; in = Wout; out = woutt; N = 1024; n0 = (t2 & 31) * 32; k0 = (t2 >> 5) * 32; }
        int tx = threadIdx.x & 31, ty = threadIdx.x >> 5;
        #pragma unroll
        for (int i = 0; i < 32; i += 8)
            tile[ty + i][tx] = in[(long)(k0 + ty + i) * N + n0 + tx];
        __syncthreads();
        #pragma unroll
        for (int i = 0; i < 32; i += 8)
            out[(long)(n0 + ty + i) * 1024 + k0 + tx] = f2bf(tile[tx][ty + i]);
    } else {
        long i = ((long)(bx - 4096) * 256 + threadIdx.x) * 4;
        float4 v = *(const float4*)&x[i];
        s16x4 o;
        o[0] = f2bf(v.x); o[1] = f2bf(v.y); o[2] = f2bf(v.z); o[3] = f2bf(v.w);
        *(s16x4*)&xb[i] = o;
    }
}

// ---------------------------------------------------------------- bf16 MFMA GEMM
// Round-4: big-tile 8-wave structure for F/B (FLOP per LDS byte) + double-buffered
// STAGE-early single-barrier K-loop (min-2-phase: prefetch next tile's
// global_load_lds at top, compute current, one __syncthreads per K-step; the
// barrier's vmcnt(0) drain lands ~a full compute-phase after issue).
// LDS layout: verified XOR-chunk (row*64 + (chunk^(row&7))*8) — conflicts
// measured 0; global source pre-swizzled so staging stays 128B-contiguous.
// MODE 0: 256x192 tile, 8 waves (wave-tile 128x48), grid 16x16 = 256 = 1/CU
//         (100% fill). QKV epilogue -> q (pre-scaled log2e/8), k, vt.
// MODE 1: 64x64 tile, 4 waves (wave-tile 32x32), grid 64x16 = 1024 = 4+/CU
//         (latency hiding for the small out-proj GEMM) -> fp32 out.
template<int MODE>
__global__ __launch_bounds__((MODE == 1) ? 256 : 512, 2) void gemm_bf16_kernel(
    const short* __restrict__ A, const short* __restrict__ Bt,
    const float* __restrict__ bias,
    short* __restrict__ qo, short* __restrict__ ko, short* __restrict__ vt,
    float* __restrict__ fout)
{
    const int K = 1024;
    constexpr int BM = (MODE == 1) ? 64 : 256;
    constexpr int BN = (MODE == 1) ? 64 : 192;
    constexpr int WM = 2;
    constexpr int WN = (MODE == 1) ? 2 : 4;
    constexpr int NW = WM * WN;                 // waves per block
    constexpr int MI = BM / WM / 16;            // m-subtiles per wave (8 / 2)
    constexpr int NJ = BN / WN / 16;            // n-subtiles per wave (3 / 2)
    constexpr int RA = BM / NW;                 // A rows staged per wave (32 / 16)
    constexpr int RB = BN / NW;                 // B rows staged per wave (24 / 16)
    constexpr int SA = RA / 8, SB = RB / 8;     // gl_lds16 sweeps (4,3 / 2,2)

    __shared__ short smem[2 * (BM + BN) * 64];  // [A buf0|A buf1|B buf0|B buf1]

    int tid  = threadIdx.x;
    int wid  = tid >> 6, lane = tid & 63;
    int wm   = wid / WN, wn = wid % WN;
    int g    = lane >> 4, l15 = lane & 15;
    int swzr = l15 & 7;
    long m0  = (long)blockIdx.x * BM;
    long n0  = (long)blockIdx.y * BN;

    f32x4 acc[MI][NJ];
    #pragma unroll
    for (int i = 0; i < MI; i++)
        #pragma unroll
        for (int j = 0; j < NJ; j++)
            acc[i][j] = (f32x4){0.f, 0.f, 0.f, 0.f};

    int srow = lane >> 3;                               // row within 8-row strip
    int sch  = ((lane & 7) ^ ((lane >> 3) & 7)) * 8;    // pre-swizzled chunk (shorts)
    const short* Abase = A  + (m0 + wid * RA + srow) * K + sch;
    const short* Bbase = Bt + (n0 + wid * RB + srow) * K + sch;
    short* adst = smem + (wid * RA) * 64;               // + buf*BM*64
    short* bdst = smem + 2 * BM * 64 + (wid * RB) * 64; // + buf*BN*64

    // prologue: stage k-tile 0 into buf 0
    #pragma unroll
    for (int s = 0; s < SA; s++) gl_lds16(Abase + (long)s * 8 * K, adst + s * 8 * 64);
    #pragma unroll
    for (int s = 0; s < SB; s++) gl_lds16(Bbase + (long)s * 8 * K, bdst + s * 8 * 64);
    __syncthreads();

    for (int k0 = 0; k0 < K; k0 += 64) {
        int cur = (k0 >> 6) & 1, nxt = cur ^ 1;
        if (k0 + 64 < K) {   // prefetch next k-tile into the other buffer
            #pragma unroll
            for (int s = 0; s < SA; s++)
                gl_lds16(Abase + (long)s * 8 * K + k0 + 64, adst + nxt * BM * 64 + s * 8 * 64);
            #pragma unroll
            for (int s = 0; s < SB; s++)
                gl_lds16(Bbase + (long)s * 8 * K + k0 + 64, bdst + nxt * BN * 64 + s * 8 * 64);
        }
        const short* Asb = smem + cur * BM * 64;
        const short* Bsb = smem + 2 * BM * 64 + cur * BN * 64;

        #pragma unroll
        for (int c = 0; c < 2; c++) {
            bf16x8 bfr[NJ];
            #pragma unroll
            for (int j = 0; j < NJ; j++)
                bfr[j] = *(const bf16x8*)&Bsb[(wn * (BN / WN) + j * 16 + l15) * 64 + (((c * 4 + g) ^ swzr) << 3)];
            bf16x8 af[MI];
            #pragma unroll
            for (int i = 0; i < MI; i++)
                af[i] = *(const bf16x8*)&Asb[(wm * (BM / WM) + i * 16 + l15) * 64 + (((c * 4 + g) ^ swzr) << 3)];
            #pragma unroll
            for (int i = 0; i < MI; i++)
                #pragma unroll
                for (int j = 0; j < NJ; j++)
                    acc[i][j] = __builtin_amdgcn_mfma_f32_16x16x32_bf16(af[i], bfr[j], acc[i][j], 0, 0, 0);
        }
        __syncthreads();   // publishes prefetch (vmcnt0) + guards cur-buf reuse
    }

    // epilogue: D[m = (lane>>4)*4 + reg][n = lane&15]
    #pragma unroll
    for (int j = 0; j < NJ; j++) {
        int n = (int)n0 + wn * (BN / WN) + j * 16 + l15;
        float bb = bias[n];
        #pragma unroll
        for (int i = 0; i < MI; i++) {
            int mrow = (int)m0 + wm * (BM / WM) + i * 16 + g * 4;
            if (MODE == 1) {
                #pragma unroll
                for (int r = 0; r < 4; r++)
                    fout[(long)(mrow + r) * 1024 + n] = acc[i][j][r] + bb;
            } else {
                if (n < 1024) {
                    const float QS = 0.125f * 1.44269504088896f;   // log2e/sqrt(dk)
                    #pragma unroll
                    for (int r = 0; r < 4; r++)
                        qo[(long)(mrow + r) * 1024 + n] = f2bf((acc[i][j][r] + bb) * QS);
                } else if (n < 2048) {
                    #pragma unroll
                    for (int r = 0; r < 4; r++)
                        ko[(long)(mrow + r) * 1024 + (n - 1024)] = f2bf(acc[i][j][r] + bb);
                } else {
                    int c = n - 2048, h = c >> 6, d = c & 63;
                    int b = mrow >> 11, t = mrow & 2047;
                    s16x4 pk;
                    #pragma unroll
                    for (int r = 0; r < 4; r++) pk[r] = f2bf(acc[i][j][r] + bb);
                    *(s16x4*)&vt[((long)((b * 16 + h) * 64 + d)) * 2048 + t] = pk;
                }
            }
        }
    }
}

// ---------------------------------------------------------------- flash attention
// grid: (TSEQ/64, BATCH*HEADS) = 1024 blocks. Round-3 version, unchanged:
// issue-bound (MfmaUtil 31 + VALUBusy 52 ~= 83%); conflicts 0; K/V L2-resident.
__global__ __launch_bounds__(256) void flash_attn_kernel(
    const short* __restrict__ qb, const short* __restrict__ kb,
    const short* __restrict__ vt, short* __restrict__ ob)
{
    __shared__ short Ks[2][64 * 64];          // [buf][key*64 + swz(chunk)*8]
    __shared__ short Vs[2][64 * 64];          // [buf][d*64 + swz(chunk)*8]

    int tid = threadIdx.x, wid = tid >> 6, lane = tid & 63;
    int g = lane >> 4, l15 = lane & 15;
    int swzr = l15 & 7;

    // XCD swizzle: 1024 blocks on 8 XCDs; cluster so XCD k owns heads [4k,4k+4)
    int fid = blockIdx.y * 32 + blockIdx.x;   // linear dispatch id (gridDim.x=32)
    int swb = (fid & 7) * 128 + (fid >> 3);
    int bh  = swb >> 5;                        // 0..31
    int qt  = swb & 31;                        // q-tile 0..31
    int b = bh >> 4, h = bh & 15;
    int q0w = qt * 64 + wid * 16;
    long qrow = (long)b * TSEQ + q0w;

    bf16x8 qf[2];
    #pragma unroll
    for (int c = 0; c < 2; c++)
        qf[c] = *(const bf16x8*)&qb[(qrow + l15) * 1024 + h * 64 + c * 32 + g * 8];

    bf16x8 ones;
    #pragma unroll
    for (int j = 0; j < 8; j++) ones[j] = (short)0x3F80;   // bf16 1.0

    f32x4 oacc[4], lacc;
    lacc = (f32x4){0.f, 0.f, 0.f, 0.f};
    #pragma unroll
    for (int jt = 0; jt < 4; jt++) oacc[jt] = (f32x4){0.f, 0.f, 0.f, 0.f};

    const short* kg = kb + ((long)b * TSEQ) * 1024 + h * 64;   // + key*1024 + d
    const short* vg = vt + ((long)bh * 64) * 2048;             // + d*2048 + key

    int ch = (((lane & 7) ^ ((lane >> 3) & 7))) * 8;   // swizzled global chunk offset
    int r0 = wid * 16 + (lane >> 3);
    int r1 = r0 + 8;
    short* kdst0 = &Ks[0][(wid * 2 + 0) * 512];
    short* kdst1 = &Ks[0][(wid * 2 + 1) * 512];
    short* vdst0 = &Vs[0][(wid * 2 + 0) * 512];
    short* vdst1 = &Vs[0][(wid * 2 + 1) * 512];

    #define STAGE(buf, kt)                                                        \
        gl_lds16(kg + (long)((kt) * 64 + r0) * 1024 + ch, kdst0 + (buf) * 4096);  \
        gl_lds16(kg + (long)((kt) * 64 + r1) * 1024 + ch, kdst1 + (buf) * 4096);  \
        gl_lds16(vg + (long)r0 * 2048 + (kt) * 64 + ch,   vdst0 + (buf) * 4096);  \
        gl_lds16(vg + (long)r1 * 2048 + (kt) * 64 + ch,   vdst1 + (buf) * 4096);

    #define BODY(cur, nxt, kt, do_pref)                                                  \
    {                                                                                    \
        if (do_pref) { STAGE(nxt, (kt) + 1) }                                            \
        bf16x8 kf[4][2], vf[4][2];                                                       \
        _Pragma("unroll")                                                                \
        for (int jt = 0; jt < 4; jt++)                                                   \
            _Pragma("unroll")                                                            \
            for (int c = 0; c < 2; c++) {                                                \
                int off = (jt * 16 + l15) * 64 + (((c * 4 + g) ^ swzr) << 3);            \
                kf[jt][c] = *(const bf16x8*)&Ks[cur][off];                               \
                vf[jt][c] = *(const bf16x8*)&Vs[cur][off];                               \
            }                                                                            \
        f32x4 s[4];                                                                      \
        _Pragma("unroll")                                                                \
        for (int jt = 0; jt < 4; jt++) {                                                 \
            f32x4 t = (f32x4){0.f, 0.f, 0.f, 0.f};                                       \
            t = __builtin_amdgcn_mfma_f32_16x16x32_bf16(kf[jt][0], qf[0], t, 0, 0, 0);   \
            t = __builtin_amdgcn_mfma_f32_16x16x32_bf16(kf[jt][1], qf[1], t, 0, 0, 0);   \
            s[jt] = t;                                                                   \
        }                                                                                \
        unsigned up[4][2];                                                               \
        _Pragma("unroll")                                                                \
        for (int jt = 0; jt < 4; jt++) {                                                 \
            float p0 = __builtin_amdgcn_exp2f(s[jt][0]);                                 \
            float p1 = __builtin_amdgcn_exp2f(s[jt][1]);                                 \
            float p2 = __builtin_amdgcn_exp2f(s[jt][2]);                                 \
            float p3 = __builtin_amdgcn_exp2f(s[jt][3]);                                 \
            up[jt][0] = cvt_pk_bf16(p0, p1);                                             \
            up[jt][1] = cvt_pk_bf16(p2, p3);                                             \
        }                                                                                \
        _Pragma("unroll")                                                                \
        for (int hh = 0; hh < 2; hh++) {                                                 \
            pl_swap(up[0][hh], up[1][hh]);                                               \
            pl_swap(up[2][hh], up[3][hh]);                                               \
        }                                                                                \
        bf16x8 pA0 = __builtin_bit_cast(bf16x8, (u32x4){up[0][0], up[0][1], up[1][0], up[1][1]}); \
        bf16x8 pA1 = __builtin_bit_cast(bf16x8, (u32x4){up[2][0], up[2][1], up[3][0], up[3][1]}); \
        lacc = __builtin_amdgcn_mfma_f32_16x16x32_bf16(pA0, ones, lacc, 0, 0, 0);        \
        lacc = __builtin_amdgcn_mfma_f32_16x16x32_bf16(pA1, ones, lacc, 0, 0, 0);        \
        _Pragma("unroll")                                                                \
        for (int jt = 0; jt < 4; jt++) {                                                 \
            oacc[jt] = __builtin_amdgcn_mfma_f32_16x16x32_bf16(pA0, vf[jt][0], oacc[jt], 0, 0, 0); \
            oacc[jt] = __builtin_amdgcn_mfma_f32_16x16x32_bf16(pA1, vf[jt][1], oacc[jt], 0, 0, 0); \
        }                                                                                \
        __syncthreads();                                                                 \
    }

    STAGE(0, 0)
    __syncthreads();

    for (int kt = 0; kt < TSEQ / 64; kt += 2) {
        BODY(0, 1, kt, 1)
        BODY(1, 0, kt + 1, (kt + 2 < TSEQ / 64))
    }
    #undef BODY
    #undef STAGE

    // oacc/lacc C-layout: row = q_local = g*4+r, col = l15. lacc columns are all
    // identical (B=ones), so the denominator for row r is lacc[r] in-lane.
    #pragma unroll
    for (int r = 0; r < 4; r++) {
        float inv = 1.f / lacc[r];
        long row = qrow + g * 4 + r;
        #pragma unroll
        for (int jt = 0; jt < 4; jt++)
            ob[row * 1024 + h * 64 + jt * 16 + l15] = f2bf(oacc[jt][r] * inv);
    }
}

// ---------------------------------------------------------------- launcher
extern "C" void kernel_launch(void* const* d_in, const int* in_sizes, int n_in,
                              void* d_out, int out_size, void* d_ws, size_t ws_size,
                              hipStream_t stream)
{
    const float* x    = (const float*)d_in[0];
    const float* Wqkv = (const float*)d_in[1];
    const float* bqkv = (const float*)d_in[2];
    const float* Wout = (const float*)d_in[3];
    const float* bout = (const float*)d_in[4];
    float* out = (float*)d_out;

    char* ws = (char*)d_ws;
    const size_t SZ_TOKD = (size_t)NTOK * 1024 * sizeof(short);   // 8 MB
    short* xb    = (short*)ws;                 ws += SZ_TOKD;
    short* wqkvt = (short*)ws;                 ws += (size_t)3072 * 1024 * sizeof(short);
    short* woutt = (short*)ws;                 ws += (size_t)1024 * 1024 * sizeof(short);
    short* qb    = (short*)ws;                 ws += SZ_TOKD;
    short* kb    = (short*)ws;                 ws += SZ_TOKD;
    short* vt    = (short*)ws;                 ws += SZ_TOKD;
    short* ob    = (short*)ws;                 ws += SZ_TOKD;
    if ((size_t)(ws - (char*)d_ws) > ws_size) return;   // workspace too small

    prep_kernel<<<8192, 256, 0, stream>>>(x, Wqkv, Wout, xb, wqkvt, woutt);

    gemm_bf16_kernel<0><<<dim3(NTOK / 256, 3072 / 192), 512, 0, stream>>>(
        xb, wqkvt, bqkv, qb, kb, vt, nullptr);

    flash_attn_kernel<<<dim3(TSEQ / 64, BATCH * HEADS), 256, 0, stream>>>(qb, kb, vt, ob);

    gemm_bf16_kernel<1><<<dim3(NTOK / 64, 1024 / 64), 256, 0, stream>>>(
        ob, woutt, bout, nullptr, nullptr, nullptr, out);
}

// Round 5
// 168.645 us; speedup vs baseline: 1.3590x; 1.0263x over previous
//
#include <hip/hip_runtime.h>

#define D_MODEL 1024
#define HEADS   16
#define DK      64
#define BATCH   2
#define TSEQ    2048
#define NTOK    (BATCH * TSEQ)   // 4096

typedef __attribute__((ext_vector_type(8))) short bf16x8;
typedef __attribute__((ext_vector_type(4))) short s16x4;
typedef __attribute__((ext_vector_type(4))) float f32x4;
typedef __attribute__((ext_vector_type(2))) unsigned u32x2;
typedef __attribute__((ext_vector_type(4))) unsigned u32x4;

__device__ __forceinline__ short f2bf(float f) {
    union { float f; unsigned u; } a;
    a.f = f;
    unsigned r = a.u + 0x7FFFu + ((a.u >> 16) & 1u);
    return (short)(r >> 16);
}
// one-instruction packed f32->bf16x2 (RNE): lo = bf16(a), hi = bf16(b)
__device__ __forceinline__ unsigned cvt_pk_bf16(float a, float b) {
    unsigned r;
    asm("v_cvt_pk_bf16_f32 %0, %1, %2" : "=v"(r) : "v"(a), "v"(b));
    return r;
}

// async global->LDS, 16B per lane. LDS dest = wave-uniform base + lane*16.
__device__ __forceinline__ void gl_lds16(const void* g, void* l) {
    __builtin_amdgcn_global_load_lds(
        (const __attribute__((address_space(1))) unsigned int*)(unsigned long long)g,
        (__attribute__((address_space(3))) unsigned int*)(unsigned int)(unsigned long long)l,
        16, 0, 0);
}

// P-fragment redistribution: permlane32_swap + permlane16_swap pair.
// after pl_swap(a=R[b], b=R[b+1]) (b in {0,2}):
//   a = fragment word for source-parity p=0, b = word for p=1
__device__ __forceinline__ void pl_swap(unsigned& a, unsigned& b) {
    u32x2 r32 = __builtin_amdgcn_permlane32_swap(a, b, false, false);
    u32x2 r16 = __builtin_amdgcn_permlane16_swap(r32[0], r32[1], false, false);
    a = r16[0]; b = r16[1];
}

// ------------------------------------------------- fused prep: transposes + cvt
__global__ __launch_bounds__(256) void prep_kernel(
    const float* __restrict__ x, const float* __restrict__ Wqkv,
    const float* __restrict__ Wout,
    short* __restrict__ xb, short* __restrict__ wqkvt, short* __restrict__ woutt)
{
    int bx = blockIdx.x;
    if (bx < 4096) {
        __shared__ float tile[32][33];
        const float* in; short* out; int N, n0, k0;
        if (bx < 3072) { in = Wqkv; out = wqkvt; N = 3072; n0 = (bx % 96) * 32; k0 = (bx / 96) * 32; }
        else { int t2 = bx - 3072; in = Wout; out = woutt; N = 1024; n0 = (t2 & 31) * 32; k0 = (t2 >> 5) * 32; }
        int tx = threadIdx.x & 31, ty = threadIdx.x >> 5;
        #pragma unroll
        for (int i = 0; i < 32; i += 8)
            tile[ty + i][tx] = in[(long)(k0 + ty + i) * N + n0 + tx];
        __syncthreads();
        #pragma unroll
        for (int i = 0; i < 32; i += 8)
            out[(long)(n0 + ty + i) * 1024 + k0 + tx] = f2bf(tile[tx][ty + i]);
    } else {
        long i = ((long)(bx - 4096) * 256 + threadIdx.x) * 4;
        float4 v = *(const float4*)&x[i];
        s16x4 o;
        o[0] = f2bf(v.x); o[1] = f2bf(v.y); o[2] = f2bf(v.z); o[3] = f2bf(v.w);
        *(s16x4*)&xb[i] = o;
    }
}

// ---------------------------------------------------------------- bf16 MFMA GEMM
// Big-tile 8/4-wave structure, double-buffered STAGE-early single-barrier K-loop.
// LDS layout: XOR-chunk (row*64 + (chunk^(row&7))*8), conflicts measured 0;
// global source pre-swizzled so staging stays 128B-contiguous.
// MODE 0: 256x192 tile, 8 waves (wave-tile 128x48), grid 16x16 = 256 = 1/CU.
// MODE 1: 128x64 tile, 4 waves (wave-tile 64x32), grid 32x16 = 512 = 2+/CU
//         (better F/B than 64x64: 12 LDS reads serve 16 MFMA per K-step).
template<int MODE>
__global__ __launch_bounds__((MODE == 1) ? 256 : 512, 2) void gemm_bf16_kernel(
    const short* __restrict__ A, const short* __restrict__ Bt,
    const float* __restrict__ bias,
    short* __restrict__ qo, short* __restrict__ ko, short* __restrict__ vt,
    float* __restrict__ fout)
{
    const int K = 1024;
    constexpr int BM = (MODE == 1) ? 128 : 256;
    constexpr int BN = (MODE == 1) ? 64 : 192;
    constexpr int WM = 2;
    constexpr int WN = (MODE == 1) ? 2 : 4;
    constexpr int NW = WM * WN;                 // waves per block
    constexpr int MI = BM / WM / 16;            // m-subtiles per wave (4 / 8)
    constexpr int NJ = BN / WN / 16;            // n-subtiles per wave (2 / 3)
    constexpr int RA = BM / NW;                 // A rows staged per wave (32 / 32)
    constexpr int RB = BN / NW;                 // B rows staged per wave (16 / 24)
    constexpr int SA = RA / 8, SB = RB / 8;     // gl_lds16 sweeps

    __shared__ short smem[2 * (BM + BN) * 64];  // [A buf0|A buf1|B buf0|B buf1]

    int tid  = threadIdx.x;
    int wid  = tid >> 6, lane = tid & 63;
    int wm   = wid / WN, wn = wid % WN;
    int g    = lane >> 4, l15 = lane & 15;
    int swzr = l15 & 7;
    long m0  = (long)blockIdx.x * BM;
    long n0  = (long)blockIdx.y * BN;

    f32x4 acc[MI][NJ];
    #pragma unroll
    for (int i = 0; i < MI; i++)
        #pragma unroll
        for (int j = 0; j < NJ; j++)
            acc[i][j] = (f32x4){0.f, 0.f, 0.f, 0.f};

    int srow = lane >> 3;                               // row within 8-row strip
    int sch  = ((lane & 7) ^ ((lane >> 3) & 7)) * 8;    // pre-swizzled chunk (shorts)
    const short* Abase = A  + (m0 + wid * RA + srow) * K + sch;
    const short* Bbase = Bt + (n0 + wid * RB + srow) * K + sch;
    short* adst = smem + (wid * RA) * 64;               // + buf*BM*64
    short* bdst = smem + 2 * BM * 64 + (wid * RB) * 64; // + buf*BN*64

    // prologue: stage k-tile 0 into buf 0
    #pragma unroll
    for (int s = 0; s < SA; s++) gl_lds16(Abase + (long)s * 8 * K, adst + s * 8 * 64);
    #pragma unroll
    for (int s = 0; s < SB; s++) gl_lds16(Bbase + (long)s * 8 * K, bdst + s * 8 * 64);
    __syncthreads();

    for (int k0 = 0; k0 < K; k0 += 64) {
        int cur = (k0 >> 6) & 1, nxt = cur ^ 1;
        if (k0 + 64 < K) {   // prefetch next k-tile into the other buffer
            #pragma unroll
            for (int s = 0; s < SA; s++)
                gl_lds16(Abase + (long)s * 8 * K + k0 + 64, adst + nxt * BM * 64 + s * 8 * 64);
            #pragma unroll
            for (int s = 0; s < SB; s++)
                gl_lds16(Bbase + (long)s * 8 * K + k0 + 64, bdst + nxt * BN * 64 + s * 8 * 64);
        }
        const short* Asb = smem + cur * BM * 64;
        const short* Bsb = smem + 2 * BM * 64 + cur * BN * 64;

        #pragma unroll
        for (int c = 0; c < 2; c++) {
            bf16x8 bfr[NJ];
            #pragma unroll
            for (int j = 0; j < NJ; j++)
                bfr[j] = *(const bf16x8*)&Bsb[(wn * (BN / WN) + j * 16 + l15) * 64 + (((c * 4 + g) ^ swzr) << 3)];
            bf16x8 af[MI];
            #pragma unroll
            for (int i = 0; i < MI; i++)
                af[i] = *(const bf16x8*)&Asb[(wm * (BM / WM) + i * 16 + l15) * 64 + (((c * 4 + g) ^ swzr) << 3)];
            #pragma unroll
            for (int i = 0; i < MI; i++)
                #pragma unroll
                for (int j = 0; j < NJ; j++)
                    acc[i][j] = __builtin_amdgcn_mfma_f32_16x16x32_bf16(af[i], bfr[j], acc[i][j], 0, 0, 0);
        }
        __syncthreads();   // publishes prefetch (vmcnt0) + guards cur-buf reuse
    }

    // epilogue: D[m = (lane>>4)*4 + reg][n = lane&15]
    #pragma unroll
    for (int j = 0; j < NJ; j++) {
        int n = (int)n0 + wn * (BN / WN) + j * 16 + l15;
        float bb = bias[n];
        #pragma unroll
        for (int i = 0; i < MI; i++) {
            int mrow = (int)m0 + wm * (BM / WM) + i * 16 + g * 4;
            if (MODE == 1) {
                #pragma unroll
                for (int r = 0; r < 4; r++)
                    fout[(long)(mrow + r) * 1024 + n] = acc[i][j][r] + bb;
            } else {
                if (n < 1024) {
                    const float QS = 0.125f * 1.44269504088896f;   // log2e/sqrt(dk)
                    #pragma unroll
                    for (int r = 0; r < 4; r++)
                        qo[(long)(mrow + r) * 1024 + n] = f2bf((acc[i][j][r] + bb) * QS);
                } else if (n < 2048) {
                    #pragma unroll
                    for (int r = 0; r < 4; r++)
                        ko[(long)(mrow + r) * 1024 + (n - 1024)] = f2bf(acc[i][j][r] + bb);
                } else {
                    int c = n - 2048, h = c >> 6, d = c & 63;
                    int b = mrow >> 11, t = mrow & 2047;
                    s16x4 pk;
                    #pragma unroll
                    for (int r = 0; r < 4; r++) pk[r] = f2bf(acc[i][j][r] + bb);
                    *(s16x4*)&vt[((long)((b * 16 + h) * 64 + d)) * 2048 + t] = pk;
                }
            }
        }
    }
}

// ---------------------------------------------------------------- flash attention
// grid: (TSEQ/128, BATCH*HEADS) = 512 blocks, block = 4 waves x 32 queries (2 qg).
// Round-4 analysis: Q-tile-64 config is LDS-BW-bound (~10 MB/CU reads); Q-tile-128
// halves per-query LDS traffic (5 MB/CU, ~21 us floor) and moves binding back to
// issue — which this rev attacks vs round-2: single-instr cvt_pk pack (-32 VALU
// per wave-BODY), XCD head-cluster swizzle (K/V L2-resident, FETCH 12 MB in r3),
// and T5 s_setprio around MFMA clusters (+4-7% attn, m191).
__global__ __launch_bounds__(256) void flash_attn_kernel(
    const short* __restrict__ qb, const short* __restrict__ kb,
    const short* __restrict__ vt, short* __restrict__ ob)
{
    __shared__ short Ks[2][64 * 64];          // [buf][key*64 + swz(chunk)*8]
    __shared__ short Vs[2][64 * 64];          // [buf][d*64 + swz(chunk)*8]

    int tid = threadIdx.x, wid = tid >> 6, lane = tid & 63;
    int g = lane >> 4, l15 = lane & 15;
    int swzr = l15 & 7;

    // XCD swizzle: 512 blocks on 8 XCDs; XCD k owns heads [4k,4k+4) (2 MB K/V per
    // XCD L2). Bijective: fid = (fid&7)*64 + fid>>3, 512 % 8 == 0.
    int fid = blockIdx.y * 16 + blockIdx.x;    // gridDim.x = 16
    int swb = (fid & 7) * 64 + (fid >> 3);
    int bh  = swb >> 4;                        // 0..31
    int qt  = swb & 15;                        // q-tile 0..15
    int b = bh >> 4, h = bh & 15;
    int q0w = qt * 128 + wid * 32;
    long qrow = (long)b * TSEQ + q0w;

    bf16x8 qf[2][2];
    #pragma unroll
    for (int qg = 0; qg < 2; qg++)
        #pragma unroll
        for (int c = 0; c < 2; c++)
            qf[qg][c] = *(const bf16x8*)&qb[(qrow + qg * 16 + l15) * 1024 + h * 64 + c * 32 + g * 8];

    bf16x8 ones;
    #pragma unroll
    for (int j = 0; j < 8; j++) ones[j] = (short)0x3F80;   // bf16 1.0

    f32x4 oacc[2][4], lacc[2];
    #pragma unroll
    for (int qg = 0; qg < 2; qg++) {
        lacc[qg] = (f32x4){0.f, 0.f, 0.f, 0.f};
        #pragma unroll
        for (int jt = 0; jt < 4; jt++) oacc[qg][jt] = (f32x4){0.f, 0.f, 0.f, 0.f};
    }

    const short* kg = kb + ((long)b * TSEQ) * 1024 + h * 64;   // + key*1024 + d
    const short* vg = vt + ((long)bh * 64) * 2048;             // + d*2048 + key

    int ch = (((lane & 7) ^ ((lane >> 3) & 7))) * 8;   // swizzled global chunk offset
    int r0 = wid * 16 + (lane >> 3);
    int r1 = r0 + 8;
    short* kdst0 = &Ks[0][(wid * 2 + 0) * 512];
    short* kdst1 = &Ks[0][(wid * 2 + 1) * 512];
    short* vdst0 = &Vs[0][(wid * 2 + 0) * 512];
    short* vdst1 = &Vs[0][(wid * 2 + 1) * 512];

    #define STAGE(buf, kt)                                                        \
        gl_lds16(kg + (long)((kt) * 64 + r0) * 1024 + ch, kdst0 + (buf) * 4096);  \
        gl_lds16(kg + (long)((kt) * 64 + r1) * 1024 + ch, kdst1 + (buf) * 4096);  \
        gl_lds16(vg + (long)r0 * 2048 + (kt) * 64 + ch,   vdst0 + (buf) * 4096);  \
        gl_lds16(vg + (long)r1 * 2048 + (kt) * 64 + ch,   vdst1 + (buf) * 4096);

    #define BODY(cur, nxt, kt, do_pref)                                                  \
    {                                                                                    \
        if (do_pref) { STAGE(nxt, (kt) + 1) }                                            \
        bf16x8 kf[4][2], vf[4][2];                                                       \
        _Pragma("unroll")                                                                \
        for (int jt = 0; jt < 4; jt++)                                                   \
            _Pragma("unroll")                                                            \
            for (int c = 0; c < 2; c++) {                                                \
                int off = (jt * 16 + l15) * 64 + (((c * 4 + g) ^ swzr) << 3);            \
                kf[jt][c] = *(const bf16x8*)&Ks[cur][off];                               \
                vf[jt][c] = *(const bf16x8*)&Vs[cur][off];                               \
            }                                                                            \
        _Pragma("unroll")                                                                \
        for (int qg = 0; qg < 2; qg++) {                                                 \
            f32x4 s[4];                                                                  \
            __builtin_amdgcn_s_setprio(1);                                               \
            _Pragma("unroll")                                                            \
            for (int jt = 0; jt < 4; jt++) {                                             \
                f32x4 t = (f32x4){0.f, 0.f, 0.f, 0.f};                                   \
                t = __builtin_amdgcn_mfma_f32_16x16x32_bf16(kf[jt][0], qf[qg][0], t, 0, 0, 0); \
                t = __builtin_amdgcn_mfma_f32_16x16x32_bf16(kf[jt][1], qf[qg][1], t, 0, 0, 0); \
                s[jt] = t;                                                               \
            }                                                                            \
            __builtin_amdgcn_s_setprio(0);                                               \
            unsigned up[4][2];                                                           \
            _Pragma("unroll")                                                            \
            for (int jt = 0; jt < 4; jt++) {                                             \
                float p0 = __builtin_amdgcn_exp2f(s[jt][0]);                             \
                float p1 = __builtin_amdgcn_exp2f(s[jt][1]);                             \
                float p2 = __builtin_amdgcn_exp2f(s[jt][2]);                             \
                float p3 = __builtin_amdgcn_exp2f(s[jt][3]);                             \
                up[jt][0] = cvt_pk_bf16(p0, p1);                                         \
                up[jt][1] = cvt_pk_bf16(p2, p3);                                         \
            }                                                                            \
            _Pragma("unroll")                                                            \
            for (int hh = 0; hh < 2; hh++) {                                             \
                pl_swap(up[0][hh], up[1][hh]);                                           \
                pl_swap(up[2][hh], up[3][hh]);                                           \
            }                                                                            \
            bf16x8 pA0 = __builtin_bit_cast(bf16x8, (u32x4){up[0][0], up[0][1], up[1][0], up[1][1]}); \
            bf16x8 pA1 = __builtin_bit_cast(bf16x8, (u32x4){up[2][0], up[2][1], up[3][0], up[3][1]}); \
            __builtin_amdgcn_s_setprio(1);                                               \
            lacc[qg] = __builtin_amdgcn_mfma_f32_16x16x32_bf16(pA0, ones, lacc[qg], 0, 0, 0); \
            lacc[qg] = __builtin_amdgcn_mfma_f32_16x16x32_bf16(pA1, ones, lacc[qg], 0, 0, 0); \
            _Pragma("unroll")                                                            \
            for (int jt = 0; jt < 4; jt++) {                                             \
                oacc[qg][jt] = __builtin_amdgcn_mfma_f32_16x16x32_bf16(pA0, vf[jt][0], oacc[qg][jt], 0, 0, 0); \
                oacc[qg][jt] = __builtin_amdgcn_mfma_f32_16x16x32_bf16(pA1, vf[jt][1], oacc[qg][jt], 0, 0, 0); \
            }                                                                            \
            __builtin_amdgcn_s_setprio(0);                                               \
        }                                                                                \
        __syncthreads();                                                                 \
    }

    STAGE(0, 0)
    __syncthreads();

    for (int kt = 0; kt < TSEQ / 64; kt += 2) {
        BODY(0, 1, kt, 1)
        BODY(1, 0, kt + 1, (kt + 2 < TSEQ / 64))
    }
    #undef BODY
    #undef STAGE

    // oacc/lacc C-layout: row = q_local = g*4+r, col = l15. lacc columns are all
    // identical (B=ones), so the denominator for row r is lacc[qg][r] in-lane.
    #pragma unroll
    for (int qg = 0; qg < 2; qg++)
        #pragma unroll
        for (int r = 0; r < 4; r++) {
            float inv = 1.f / lacc[qg][r];
            long row = qrow + qg * 16 + g * 4 + r;
            #pragma unroll
            for (int jt = 0; jt < 4; jt++)
                ob[row * 1024 + h * 64 + jt * 16 + l15] = f2bf(oacc[qg][jt][r] * inv);
        }
}

// ---------------------------------------------------------------- launcher
extern "C" void kernel_launch(void* const* d_in, const int* in_sizes, int n_in,
                              void* d_out, int out_size, void* d_ws, size_t ws_size,
                              hipStream_t stream)
{
    const float* x    = (const float*)d_in[0];
    const float* Wqkv = (const float*)d_in[1];
    const float* bqkv = (const float*)d_in[2];
    const float* Wout = (const float*)d_in[3];
    const float* bout = (const float*)d_in[4];
    float* out = (float*)d_out;

    char* ws = (char*)d_ws;
    const size_t SZ_TOKD = (size_t)NTOK * 1024 * sizeof(short);   // 8 MB
    short* xb    = (short*)ws;                 ws += SZ_TOKD;
    short* wqkvt = (short*)ws;                 ws += (size_t)3072 * 1024 * sizeof(short);
    short* woutt = (short*)ws;                 ws += (size_t)1024 * 1024 * sizeof(short);
    short* qb    = (short*)ws;                 ws += SZ_TOKD;
    short* kb    = (short*)ws;                 ws += SZ_TOKD;
    short* vt    = (short*)ws;                 ws += SZ_TOKD;
    short* ob    = (short*)ws;                 ws += SZ_TOKD;
    if ((size_t)(ws - (char*)d_ws) > ws_size) return;   // workspace too small

    prep_kernel<<<8192, 256, 0, stream>>>(x, Wqkv, Wout, xb, wqkvt, woutt);

    gemm_bf16_kernel<0><<<dim3(NTOK / 256, 3072 / 192), 512, 0, stream>>>(
        xb, wqkvt, bqkv, qb, kb, vt, nullptr);

    flash_attn_kernel<<<dim3(TSEQ / 128, BATCH * HEADS), 256, 0, stream>>>(qb, kb, vt, ob);

    gemm_bf16_kernel<1><<<dim3(NTOK / 128, 1024 / 64), 256, 0, stream>>>(
        ob, woutt, bout, nullptr, nullptr, nullptr, out);
}